// Round 12
// baseline (307.591 us; speedup 1.0000x reference)
//
#include <hip/hip_runtime.h>
#include <hip/hip_bf16.h>

#define N_    64
#define C_    64      // C_in == C_out
#define T_    300
#define V_    25
#define K_    3
#define KT_   9
#define PAD_  4

typedef short bf16x8 __attribute__((ext_vector_type(8)));
typedef float f32x4  __attribute__((ext_vector_type(4)));

static __device__ __forceinline__ unsigned short f2bf(float f) {
    __hip_bfloat16 h = __float2bfloat16(f);
    return __builtin_bit_cast(unsigned short, h);
}
static __device__ __forceinline__ unsigned int pk2(float a, float b) {
    return (unsigned int)f2bf(a) | ((unsigned int)f2bf(b) << 16);
}
static __device__ __forceinline__ float bfhi(unsigned int u) {   // low bf16 -> f32
    return __builtin_bit_cast(float, u << 16);
}
static __device__ __forceinline__ float bflo(unsigned int u) {   // high bf16 -> f32
    return __builtin_bit_cast(float, u & 0xffff0000u);
}
static __device__ __forceinline__ float bf2f(unsigned short u) {
    return __builtin_bit_cast(float, (unsigned int)u << 16);
}

// ---------------------------------------------------------------------------
// prep: weight tables (bf16, MFMA layouts) + fused GCN bias table.
// ---------------------------------------------------------------------------
__global__ __launch_bounds__(256) void prep_kernel(
    const float* __restrict__ Wt, const float* __restrict__ Wg,
    const float* __restrict__ bg, const float* __restrict__ A,
    unsigned short* __restrict__ Wtb, unsigned short* __restrict__ Wgbt,
    unsigned short* __restrict__ bias2b, unsigned short* __restrict__ Abt)
{
    int i = blockIdx.x * 256 + threadIdx.x;
    if (i < 9*64*64) {
        int kt = i >> 12, r = i & 4095, o = r >> 6, c = r & 63;
        Wtb[i] = f2bf(Wt[(size_t)(o*64 + c)*9 + kt]);
    }
    int j = i - 9*64*64;
    if (j >= 0 && j < 64*192) {
        int o = j / 192, kc = j - 192*(j/192);
        int k = kc >> 6, ci = kc & 63;
        Wgbt[j] = f2bf(Wg[(size_t)(k*64 + o)*64 + ci]);
    }
    int m = j - 64*192;
    if (m >= 0 && m < 64*25) {
        int c = m / 25, w = m - 25*(m/25);
        float s = 0.f;
        for (int k = 0; k < 3; ++k) {
            float col = 0.f;
            for (int v = 0; v < 25; ++v) col += A[k*625 + v*25 + w];
            s += bg[k*64 + c] * col;
        }
        bias2b[w*64 + c] = f2bf(s);
    }
    int p = m - 64*25;
    if (p >= 0 && p < 3*32*40) {
        int k = p / 1280, r = p - 1280*k, w = r / 40, v = r - 40*(r/40);
        float val = (w < 25 && v < 25) ? A[k*625 + v*25 + w] : 0.f;
        Abt[p] = f2bf(val);
    }
}

// ---------------------------------------------------------------------------
// GCN: re-tiled to 20-t blocks -> grid 960, SAME bid->(n,t) map as tcn, so
// y2 producer and consumer land on the same XCD (L2-local y2).
// ---------------------------------------------------------------------------
#define GSUB   20
#define GGRP   (T_/GSUB)     // 15
#define NGBLK  (N_*GGRP)     // 960

__global__ __launch_bounds__(256, 5) void gcn_kernel(
    const float* __restrict__ x,
    const unsigned short* __restrict__ Wgbt,
    const unsigned short* __restrict__ Abt,
    const unsigned short* __restrict__ bias2b,
    unsigned short* __restrict__ y2)
{
    __shared__ unsigned short xslab[64*40];    // [ci][40e]  80B rows
    __shared__ unsigned short xa[32*200];      // [w][200e] 400B rows
    __shared__ unsigned int   bias2L[25*34];   // [w][34 u32]

    const int tid  = threadIdx.x;
    const int n    = blockIdx.x / GGRP;
    const int tg   = (blockIdx.x % GGRP) * GSUB;
    const int lane = tid & 63, wave = tid >> 6;
    const int l15  = lane & 15, lq = lane >> 4;

    bf16x8 wfrag[6], afrag[6];
    #pragma unroll
    for (int cb = 0; cb < 6; ++cb) {
        wfrag[cb] = *(const bf16x8*)(Wgbt + (wave*16 + l15)*192 + cb*32 + lq*8);
        asm volatile("" : "+v"(wfrag[cb]));
    }
    #pragma unroll
    for (int s = 0; s < 6; ++s) {   // s = k*2 + nt
        afrag[s] = *(const bf16x8*)(Abt + ((s >> 1)*32 + (s & 1)*16 + l15)*40 + lq*8);
        asm volatile("" : "+v"(afrag[s]));
    }

    for (int i = tid; i < 800; i += 256)
        bias2L[(i >> 5)*34 + (i & 31)] = ((const unsigned int*)bias2b)[i];
    if (tid < 192) {
        int r = tid / 3, z = tid - 3*(tid/3);
        ((unsigned int*)xslab)[r*20 + 13 + z] = 0u;
    }
    #pragma unroll
    for (int s = 0; s < 4; ++s) {
        int slot = tid + s*256;
        if (slot < 64*13) {
            int row = slot/13, sl = slot - 13*row;
            const float* xr = x + ((size_t)(n*C_ + row)*T_ + tg)*V_;
            float f0, f1;
            if (sl < 12) { float2 t2 = *(const float2*)(xr + 2*sl); f0 = t2.x; f1 = t2.y; }
            else         { f0 = xr[24]; f1 = 0.f; }
            ((unsigned int*)xslab)[row*20 + sl] = pk2(f0, f1);
        }
    }
    __syncthreads();

    for (int j = 0; j < GSUB; ++j) {
        const int t = tg + j;
        float2 Lr[4];
        const bool hn = (j + 1 < GSUB);
        if (hn) {
            #pragma unroll
            for (int s = 0; s < 4; ++s) {
                int slot = tid + s*256;
                if (slot < 64*13) {
                    int row = slot/13, sl = slot - 13*row;
                    const float* xr = x + ((size_t)(n*C_ + row)*T_ + t + 1)*V_;
                    if (sl < 12) Lr[s] = *(const float2*)(xr + 2*sl);
                    else         { Lr[s].x = xr[24]; Lr[s].y = 0.f; }
                }
            }
        }
        {
            bf16x8 xf = *(const bf16x8*)(xslab + (wave*16 + l15)*40 + lq*8);
            #pragma unroll
            for (int s = 0; s < 6; ++s) {
                f32x4 d = {};
                d = __builtin_amdgcn_mfma_f32_16x16x32_bf16(xf, afrag[s], d, 0, 0, 0);
                const int w = (s & 1)*16 + l15;
                if (w < 25) {
                    const int k = s >> 1;
                    unsigned long long pv = (unsigned long long)pk2(d[0], d[1])
                                          | ((unsigned long long)pk2(d[2], d[3]) << 32);
                    *(unsigned long long*)((char*)xa + w*400 + k*128 + wave*32 + lq*8) = pv;
                }
            }
        }
        __syncthreads();
        {
            f32x4 acc0 = {}, acc1 = {};
            #pragma unroll
            for (int cb = 0; cb < 6; ++cb) {
                bf16x8 b0 = *(const bf16x8*)((const char*)xa + l15*400      + cb*64 + lq*16);
                bf16x8 b1 = *(const bf16x8*)((const char*)xa + (16+l15)*400 + cb*64 + lq*16);
                acc0 = __builtin_amdgcn_mfma_f32_16x16x32_bf16(wfrag[cb], b0, acc0, 0, 0, 0);
                acc1 = __builtin_amdgcn_mfma_f32_16x16x32_bf16(wfrag[cb], b1, acc1, 0, 0, 0);
            }
            const int o0 = wave*16 + lq*4;
            {
                const int col = l15;
                unsigned int bu0 = bias2L[col*34 + (o0 >> 1)];
                unsigned int bu1 = bias2L[col*34 + (o0 >> 1) + 1];
                float v0 = acc0[0] + bfhi(bu0), v1 = acc0[1] + bflo(bu0);
                float v2 = acc0[2] + bfhi(bu1), v3 = acc0[3] + bflo(bu1);
                const size_t gcol = ((size_t)n*T_ + t)*V_ + col;
                *(unsigned long long*)(y2 + gcol*64 + o0) =
                      (unsigned long long)pk2(v0, v1)
                    | ((unsigned long long)pk2(v2, v3) << 32);
            }
            if (l15 < 9) {
                const int col = 16 + l15;
                unsigned int bu0 = bias2L[col*34 + (o0 >> 1)];
                unsigned int bu1 = bias2L[col*34 + (o0 >> 1) + 1];
                float v0 = acc1[0] + bfhi(bu0), v1 = acc1[1] + bflo(bu0);
                float v2 = acc1[2] + bfhi(bu1), v3 = acc1[3] + bflo(bu1);
                const size_t gcol = ((size_t)n*T_ + t)*V_ + col;
                *(unsigned long long*)(y2 + gcol*64 + o0) =
                      (unsigned long long)pk2(v0, v1)
                    | ((unsigned long long)pk2(v2, v3) << 32);
            }
        }
        if (hn) {
            #pragma unroll
            for (int s = 0; s < 4; ++s) {
                int slot = tid + s*256;
                if (slot < 64*13) {
                    int row = slot/13, sl = slot - 13*row;
                    ((unsigned int*)xslab)[row*20 + sl] = pk2(Lr[s].x, Lr[s].y);
                }
            }
        }
        __syncthreads();
    }
}

// ---------------------------------------------------------------------------
// TCN v6 = R10 + T14 async-stage: batched reg loads (6 outstanding/thread),
// phase-1 loads ISSUED before phase-0 MFMA (latency hides under MFMA),
// ds_writes after the barrier. 3 barriers total. 8 waves, 2 blocks/CU.
// ---------------------------------------------------------------------------
#define TTT    20
#define TCOLS  (TTT*V_)         // 500
#define SLABC  712              // 500 + 200 halo + 12 overrun pad
#define TTILES (T_/TTT)         // 15
#define NBLK   (N_*TTILES)      // 960
#define NCHK   (SLABC*4)        // 2848 16B-chunks per phase

template<int BF>
__global__ __launch_bounds__(512, 2) void tcn_kernel(
    const unsigned short* __restrict__ y2, const unsigned short* __restrict__ Wtb,
    const float* __restrict__ bt,
    unsigned short* __restrict__ y3b, float* __restrict__ y3f,
    float* __restrict__ psum, float* __restrict__ psq)
{
    __shared__ unsigned short slab[SLABC*40];   // 56,960 B
    __shared__ float s_sum[64], s_sq[64];

    const int tid = threadIdx.x;
    const int n  = blockIdx.x / TTILES;
    const int t0 = (blockIdx.x % TTILES) * TTT;
    const int lane = tid & 63, wave = tid >> 6;
    const int l15 = lane & 15, lq = lane >> 4;
    const int colw = wave * 64;

    if (tid < 64) { s_sum[tid] = 0.f; s_sq[tid] = 0.f; }

    const int lo = (t0 < PAD_) ? (PAD_ - t0)*V_ : 0;
    const int hi = (t0 + TTT + PAD_ > T_) ? (T_ + PAD_ - t0)*V_ : SLABC;
    const long gbase = ((long)n*T_*V_ + (long)(t0 - PAD_)*V_)*64;

    float4 st[6];

    // ---- load phase 0 (batched: all 6 loads in flight before any write)
    #pragma unroll
    for (int k = 0; k < 6; ++k) {
        int i = tid + k*512;
        float4 v = {0.f, 0.f, 0.f, 0.f};
        if (i < NCHK) {
            int col = i >> 2, ck = i & 3;
            if (col >= lo && col < hi)
                v = *(const float4*)(y2 + gbase + (long)col*64 + ck*8);
        }
        st[k] = v;
    }
    #pragma unroll
    for (int k = 0; k < 6; ++k) {
        int i = tid + k*512;
        if (i < NCHK) {
            int col = i >> 2, ck = i & 3;
            *(float4*)((char*)slab + col*80 + ck*16) = st[k];
        }
    }
    __syncthreads();                      // barrier 1: slab(h0) visible

    // ---- issue phase-1 loads NOW (hide under MFMA of phase 0)
    #pragma unroll
    for (int k = 0; k < 6; ++k) {
        int i = tid + k*512;
        float4 v = {0.f, 0.f, 0.f, 0.f};
        if (i < NCHK) {
            int col = i >> 2, ck = i & 3;
            if (col >= lo && col < hi)
                v = *(const float4*)(y2 + gbase + (long)col*64 + 32 + ck*8);
        }
        st[k] = v;
    }

    f32x4 acc[4][4] = {};
    // ---- MFMA phase 0 (channels 0..31)
    #pragma unroll
    for (int kt = 0; kt < 9; ++kt) {
        bf16x8 a[4];
        #pragma unroll
        for (int mt = 0; mt < 4; ++mt)
            a[mt] = *(const bf16x8*)(Wtb + kt*4096 + (mt*16 + l15)*64 + lq*8);
        #pragma unroll
        for (int nf = 0; nf < 4; ++nf) {
            const int col = colw + nf*16 + l15 + kt*25;   // <= 711
            bf16x8 b = *(const bf16x8*)((const char*)slab + col*80 + lq*16);
            #pragma unroll
            for (int mt = 0; mt < 4; ++mt)
                acc[mt][nf] = __builtin_amdgcn_mfma_f32_16x16x32_bf16(
                    a[mt], b, acc[mt][nf], 0, 0, 0);
        }
    }
    __syncthreads();                      // barrier 2: slab(h0) readers done

    // ---- write phase 1 into slab
    #pragma unroll
    for (int k = 0; k < 6; ++k) {
        int i = tid + k*512;
        if (i < NCHK) {
            int col = i >> 2, ck = i & 3;
            *(float4*)((char*)slab + col*80 + ck*16) = st[k];
        }
    }
    __syncthreads();                      // barrier 3: slab(h1) visible

    // ---- MFMA phase 1 (channels 32..63)
    #pragma unroll
    for (int kt = 0; kt < 9; ++kt) {
        bf16x8 a[4];
        #pragma unroll
        for (int mt = 0; mt < 4; ++mt)
            a[mt] = *(const bf16x8*)(Wtb + kt*4096 + (mt*16 + l15)*64 + 32 + lq*8);
        #pragma unroll
        for (int nf = 0; nf < 4; ++nf) {
            const int col = colw + nf*16 + l15 + kt*25;
            bf16x8 b = *(const bf16x8*)((const char*)slab + col*80 + lq*16);
            #pragma unroll
            for (int mt = 0; mt < 4; ++mt)
                acc[mt][nf] = __builtin_amdgcn_mfma_f32_16x16x32_bf16(
                    a[mt], b, acc[mt][nf], 0, 0, 0);
        }
    }

    // ---- epilogue: bias + direct stores + BN partials (shuffle-reduced)
    float ls[16], lsq[16];
    #pragma unroll
    for (int e = 0; e < 16; ++e) { ls[e] = 0.f; lsq[e] = 0.f; }

    #pragma unroll
    for (int mt = 0; mt < 4; ++mt) {
        #pragma unroll
        for (int r = 0; r < 4; ++r) {
            const int e = mt*4 + r;
            const int o = mt*16 + lq*4 + r;
            const float bias = bt[o];
            #pragma unroll
            for (int nf = 0; nf < 4; ++nf) {
                const int col = colw + nf*16 + l15;
                if (col < TCOLS) {
                    const float val = acc[mt][nf][r] + bias;
                    const size_t idx = (size_t)(n*C_ + o)*(T_*V_) + t0*V_ + col;
                    if (BF) y3b[idx] = f2bf(val);
                    else    y3f[idx] = val;
                    ls[e] += val; lsq[e] += val*val;
                }
            }
        }
    }

    __syncthreads();
    #pragma unroll
    for (int e = 0; e < 16; ++e) {
        float a = ls[e], b = lsq[e];
        a += __shfl_xor(a, 1); a += __shfl_xor(a, 2);
        a += __shfl_xor(a, 4); a += __shfl_xor(a, 8);
        b += __shfl_xor(b, 1); b += __shfl_xor(b, 2);
        b += __shfl_xor(b, 4); b += __shfl_xor(b, 8);
        if (l15 == 0) {
            const int o = (e >> 2)*16 + lq*4 + (e & 3);
            atomicAdd(&s_sum[o], a);
            atomicAdd(&s_sq[o], b);
        }
    }
    __syncthreads();
    if (tid < 64) {
        psum[(size_t)tid*NBLK + blockIdx.x] = s_sum[tid];
        psq [(size_t)tid*NBLK + blockIdx.x] = s_sq [tid];
    }
}

// ---------------------------------------------------------------------------
// stats: reduce partials -> per-channel scale/shift
// ---------------------------------------------------------------------------
__global__ __launch_bounds__(256) void stats_kernel(
    const float* __restrict__ psum, const float* __restrict__ psq,
    const float* __restrict__ gamma, const float* __restrict__ beta,
    float* __restrict__ sb)
{
    const int o = blockIdx.x;
    const int tid = threadIdx.x;
    float s = 0.f, q = 0.f;
    for (int i = tid; i < NBLK; i += 256) {
        s += psum[(size_t)o*NBLK + i];
        q += psq [(size_t)o*NBLK + i];
    }
    __shared__ float rs[256], rq[256];
    rs[tid] = s; rq[tid] = q;
    __syncthreads();
    for (int off = 128; off > 0; off >>= 1) {
        if (tid < off) { rs[tid] += rs[tid + off]; rq[tid] += rq[tid + off]; }
        __syncthreads();
    }
    if (tid == 0) {
        const float cnt = (float)(N_ * T_ * V_);
        float mean = rs[0] / cnt;
        float var  = rq[0] / cnt - mean * mean;
        float rstd = rsqrtf(var + 1e-5f);
        float sc   = gamma[o] * rstd;
        sb[o]      = sc;
        sb[C_ + o] = beta[o] - mean * sc;
    }
}

// ---------------------------------------------------------------------------
// BN + residual + ReLU (grid-stride, 2048 blocks)
// ---------------------------------------------------------------------------
__global__ __launch_bounds__(256) void bn_res_relu_bf16_kernel(
    const float* __restrict__ x, const unsigned short* __restrict__ y3b,
    const float* __restrict__ sb, float* __restrict__ out)
{
    const size_t total4 = (size_t)N_ * C_ * T_ * V_ / 4;  // 7,680,000
    const size_t stride = (size_t)gridDim.x * 256;
    for (size_t i4 = (size_t)blockIdx.x * 256 + threadIdx.x; i4 < total4; i4 += stride) {
        const int c = (int)((i4 / (T_ * V_ / 4)) % C_);
        const float sc = sb[c], sh = sb[C_ + c];
        ushort4 yv = ((const ushort4*)y3b)[i4];
        float4 xv = ((const float4*)x)[i4];
        float4 o;
        o.x = fmaxf(bf2f(yv.x) * sc + sh + xv.x, 0.0f);
        o.y = fmaxf(bf2f(yv.y) * sc + sh + xv.y, 0.0f);
        o.z = fmaxf(bf2f(yv.z) * sc + sh + xv.z, 0.0f);
        o.w = fmaxf(bf2f(yv.w) * sc + sh + xv.w, 0.0f);
        ((float4*)out)[i4] = o;
    }
}

__global__ __launch_bounds__(256) void bn_res_relu_f32_kernel(
    const float* __restrict__ x, const float* __restrict__ sb,
    float* __restrict__ y)
{
    const size_t total4 = (size_t)N_ * C_ * T_ * V_ / 4;
    const size_t stride = (size_t)gridDim.x * 256;
    for (size_t i4 = (size_t)blockIdx.x * 256 + threadIdx.x; i4 < total4; i4 += stride) {
        const int c = (int)((i4 / (T_ * V_ / 4)) % C_);
        const float sc = sb[c], sh = sb[C_ + c];
        float4 yv = ((const float4*)y)[i4];
        float4 xv = ((const float4*)x)[i4];
        float4 o;
        o.x = fmaxf(yv.x * sc + sh + xv.x, 0.0f);
        o.y = fmaxf(yv.y * sc + sh + xv.y, 0.0f);
        o.z = fmaxf(yv.z * sc + sh + xv.z, 0.0f);
        o.w = fmaxf(yv.w * sc + sh + xv.w, 0.0f);
        ((float4*)y)[i4] = o;
    }
}

// ---------------------------------------------------------------------------
extern "C" void kernel_launch(void* const* d_in, const int* in_sizes, int n_in,
                              void* d_out, int out_size, void* d_ws, size_t ws_size,
                              hipStream_t stream)
{
    const float* x     = (const float*)d_in[0];
    const float* A     = (const float*)d_in[1];
    const float* wg    = (const float*)d_in[2];
    const float* bg    = (const float*)d_in[3];
    const float* wt    = (const float*)d_in[4];
    const float* bt    = (const float*)d_in[5];
    const float* gamma = (const float*)d_in[6];
    const float* beta  = (const float*)d_in[7];
    float* out = (float*)d_out;

    char* wsb = (char*)d_ws;
    const size_t Y2B   = 61440000;                 // y2 bf16
    const size_t Y3B   = 61440000;                 // y3 bf16 (optional)
    const size_t PSB   = (size_t)C_ * NBLK * 4;    // 245,760 each
    const size_t TABLE = 2*PSB + 512 + 73728 + 24576 + 3200 + 7680;
    const bool usebf = ws_size >= Y2B + Y3B + TABLE;

    unsigned short* y2  = (unsigned short*)wsb;
    unsigned short* y3b = (unsigned short*)(wsb + Y2B);
    const size_t base2  = usebf ? (Y2B + Y3B) : Y2B;
    float* psum            = (float*)(wsb + base2);
    float* psq             = (float*)(wsb + base2 + PSB);
    float* sb              = (float*)(wsb + base2 + 2*PSB);
    unsigned short* Wtb    = (unsigned short*)(wsb + base2 + 2*PSB + 512);
    unsigned short* Wgbt   = (unsigned short*)(wsb + base2 + 2*PSB + 512 + 73728);
    unsigned short* bias2b = (unsigned short*)(wsb + base2 + 2*PSB + 512 + 73728 + 24576);
    unsigned short* Abt    = (unsigned short*)(wsb + base2 + 2*PSB + 512 + 73728 + 24576 + 3200);

    prep_kernel<<<214, 256, 0, stream>>>(wt, wg, bg, A, Wtb, Wgbt, bias2b, Abt);
    gcn_kernel<<<NGBLK, 256, 0, stream>>>(x, Wgbt, Abt, bias2b, y2);
    if (usebf)
        tcn_kernel<1><<<NBLK, 512, 0, stream>>>(y2, Wtb, bt, y3b, out, psum, psq);
    else
        tcn_kernel<0><<<NBLK, 512, 0, stream>>>(y2, Wtb, bt, y3b, out, psum, psq);
    stats_kernel<<<C_, 256, 0, stream>>>(psum, psq, gamma, beta, sb);
    if (usebf)
        bn_res_relu_bf16_kernel<<<2048, 256, 0, stream>>>(x, y3b, sb, out);
    else
        bn_res_relu_f32_kernel<<<2048, 256, 0, stream>>>(x, sb, out);
}

// Round 13
// 278.145 us; speedup vs baseline: 1.1059x; 1.1059x over previous
//
#include <hip/hip_runtime.h>
#include <hip/hip_bf16.h>

#define N_    64
#define C_    64      // C_in == C_out
#define T_    300
#define V_    25
#define K_    3
#define KT_   9
#define PAD_  4

typedef short bf16x8 __attribute__((ext_vector_type(8)));
typedef float f32x4  __attribute__((ext_vector_type(4)));

static __device__ __forceinline__ unsigned short f2bf(float f) {
    __hip_bfloat16 h = __float2bfloat16(f);
    return __builtin_bit_cast(unsigned short, h);
}
static __device__ __forceinline__ unsigned int pk2(float a, float b) {
    return (unsigned int)f2bf(a) | ((unsigned int)f2bf(b) << 16);
}
static __device__ __forceinline__ float bfhi(unsigned int u) {   // low bf16 -> f32
    return __builtin_bit_cast(float, u << 16);
}
static __device__ __forceinline__ float bflo(unsigned int u) {   // high bf16 -> f32
    return __builtin_bit_cast(float, u & 0xffff0000u);
}

// ---------------------------------------------------------------------------
// prep: weight tables (bf16, MFMA layouts) + fused GCN bias table.
// ---------------------------------------------------------------------------
__global__ __launch_bounds__(256) void prep_kernel(
    const float* __restrict__ Wt, const float* __restrict__ Wg,
    const float* __restrict__ bg, const float* __restrict__ A,
    unsigned short* __restrict__ Wtb, unsigned short* __restrict__ Wgbt,
    unsigned short* __restrict__ bias2b, unsigned short* __restrict__ Abt)
{
    int i = blockIdx.x * 256 + threadIdx.x;
    if (i < 9*64*64) {
        int kt = i >> 12, r = i & 4095, o = r >> 6, c = r & 63;
        Wtb[i] = f2bf(Wt[(size_t)(o*64 + c)*9 + kt]);
    }
    int j = i - 9*64*64;
    if (j >= 0 && j < 64*192) {
        int o = j / 192, kc = j - 192*(j/192);
        int k = kc >> 6, ci = kc & 63;
        Wgbt[j] = f2bf(Wg[(size_t)(k*64 + o)*64 + ci]);
    }
    int m = j - 64*192;
    if (m >= 0 && m < 64*25) {
        int c = m / 25, w = m - 25*(m/25);
        float s = 0.f;
        for (int k = 0; k < 3; ++k) {
            float col = 0.f;
            for (int v = 0; v < 25; ++v) col += A[k*625 + v*25 + w];
            s += bg[k*64 + c] * col;
        }
        bias2b[w*64 + c] = f2bf(s);
    }
    int p = m - 64*25;
    if (p >= 0 && p < 3*32*40) {
        int k = p / 1280, r = p - 1280*k, w = r / 40, v = r - 40*(r/40);
        float val = (w < 25 && v < 25) ? A[k*625 + v*25 + w] : 0.f;
        Abt[p] = f2bf(val);
    }
}

// ---------------------------------------------------------------------------
// GCN: R5-proven config — grid 1280 = 5 blocks/CU, all co-resident.
// ---------------------------------------------------------------------------
#define GSUB   15
#define GGRP   (T_/GSUB)     // 20
#define NGBLK  (N_*GGRP)     // 1280

__global__ __launch_bounds__(256, 5) void gcn_kernel(
    const float* __restrict__ x,
    const unsigned short* __restrict__ Wgbt,
    const unsigned short* __restrict__ Abt,
    const unsigned short* __restrict__ bias2b,
    unsigned short* __restrict__ y2)
{
    __shared__ unsigned short xslab[64*40];    // [ci][40e]  80B rows
    __shared__ unsigned short xa[32*200];      // [w][200e] 400B rows
    __shared__ unsigned int   bias2L[25*34];   // [w][34 u32]

    const int tid  = threadIdx.x;
    const int n    = blockIdx.x / GGRP;
    const int tg   = (blockIdx.x % GGRP) * GSUB;
    const int lane = tid & 63, wave = tid >> 6;
    const int l15  = lane & 15, lq = lane >> 4;

    bf16x8 wfrag[6], afrag[6];
    #pragma unroll
    for (int cb = 0; cb < 6; ++cb) {
        wfrag[cb] = *(const bf16x8*)(Wgbt + (wave*16 + l15)*192 + cb*32 + lq*8);
        asm volatile("" : "+v"(wfrag[cb]));
    }
    #pragma unroll
    for (int s = 0; s < 6; ++s) {   // s = k*2 + nt
        afrag[s] = *(const bf16x8*)(Abt + ((s >> 1)*32 + (s & 1)*16 + l15)*40 + lq*8);
        asm volatile("" : "+v"(afrag[s]));
    }

    for (int i = tid; i < 800; i += 256)
        bias2L[(i >> 5)*34 + (i & 31)] = ((const unsigned int*)bias2b)[i];
    if (tid < 192) {
        int r = tid / 3, z = tid - 3*(tid/3);
        ((unsigned int*)xslab)[r*20 + 13 + z] = 0u;
    }
    #pragma unroll
    for (int s = 0; s < 4; ++s) {
        int slot = tid + s*256;
        if (slot < 64*13) {
            int row = slot/13, sl = slot - 13*row;
            const float* xr = x + ((size_t)(n*C_ + row)*T_ + tg)*V_;
            float f0, f1;
            if (sl < 12) { float2 t2 = *(const float2*)(xr + 2*sl); f0 = t2.x; f1 = t2.y; }
            else         { f0 = xr[24]; f1 = 0.f; }
            ((unsigned int*)xslab)[row*20 + sl] = pk2(f0, f1);
        }
    }
    __syncthreads();

    for (int j = 0; j < GSUB; ++j) {
        const int t = tg + j;
        float2 Lr[4];
        const bool hn = (j + 1 < GSUB);
        if (hn) {
            #pragma unroll
            for (int s = 0; s < 4; ++s) {
                int slot = tid + s*256;
                if (slot < 64*13) {
                    int row = slot/13, sl = slot - 13*row;
                    const float* xr = x + ((size_t)(n*C_ + row)*T_ + t + 1)*V_;
                    if (sl < 12) Lr[s] = *(const float2*)(xr + 2*sl);
                    else         { Lr[s].x = xr[24]; Lr[s].y = 0.f; }
                }
            }
        }
        {
            bf16x8 xf = *(const bf16x8*)(xslab + (wave*16 + l15)*40 + lq*8);
            #pragma unroll
            for (int s = 0; s < 6; ++s) {
                f32x4 d = {};
                d = __builtin_amdgcn_mfma_f32_16x16x32_bf16(xf, afrag[s], d, 0, 0, 0);
                const int w = (s & 1)*16 + l15;
                if (w < 25) {
                    const int k = s >> 1;
                    unsigned long long pv = (unsigned long long)pk2(d[0], d[1])
                                          | ((unsigned long long)pk2(d[2], d[3]) << 32);
                    *(unsigned long long*)((char*)xa + w*400 + k*128 + wave*32 + lq*8) = pv;
                }
            }
        }
        __syncthreads();
        {
            f32x4 acc0 = {}, acc1 = {};
            #pragma unroll
            for (int cb = 0; cb < 6; ++cb) {
                bf16x8 b0 = *(const bf16x8*)((const char*)xa + l15*400      + cb*64 + lq*16);
                bf16x8 b1 = *(const bf16x8*)((const char*)xa + (16+l15)*400 + cb*64 + lq*16);
                acc0 = __builtin_amdgcn_mfma_f32_16x16x32_bf16(wfrag[cb], b0, acc0, 0, 0, 0);
                acc1 = __builtin_amdgcn_mfma_f32_16x16x32_bf16(wfrag[cb], b1, acc1, 0, 0, 0);
            }
            const int o0 = wave*16 + lq*4;
            {
                const int col = l15;
                unsigned int bu0 = bias2L[col*34 + (o0 >> 1)];
                unsigned int bu1 = bias2L[col*34 + (o0 >> 1) + 1];
                float v0 = acc0[0] + bfhi(bu0), v1 = acc0[1] + bflo(bu0);
                float v2 = acc0[2] + bfhi(bu1), v3 = acc0[3] + bflo(bu1);
                const size_t gcol = ((size_t)n*T_ + t)*V_ + col;
                *(unsigned long long*)(y2 + gcol*64 + o0) =
                      (unsigned long long)pk2(v0, v1)
                    | ((unsigned long long)pk2(v2, v3) << 32);
            }
            if (l15 < 9) {
                const int col = 16 + l15;
                unsigned int bu0 = bias2L[col*34 + (o0 >> 1)];
                unsigned int bu1 = bias2L[col*34 + (o0 >> 1) + 1];
                float v0 = acc1[0] + bfhi(bu0), v1 = acc1[1] + bflo(bu0);
                float v2 = acc1[2] + bfhi(bu1), v3 = acc1[3] + bflo(bu1);
                const size_t gcol = ((size_t)n*T_ + t)*V_ + col;
                *(unsigned long long*)(y2 + gcol*64 + o0) =
                      (unsigned long long)pk2(v0, v1)
                    | ((unsigned long long)pk2(v2, v3) << 32);
            }
        }
        if (hn) {
            #pragma unroll
            for (int s = 0; s < 4; ++s) {
                int slot = tid + s*256;
                if (slot < 64*13) {
                    int row = slot/13, sl = slot - 13*row;
                    ((unsigned int*)xslab)[row*20 + sl] = pk2(Lr[s].x, Lr[s].y);
                }
            }
        }
        __syncthreads();
    }
}

// ---------------------------------------------------------------------------
// TCN = R4's exact proven structure: 256 threads, two 32-channel K phases,
// slab 712x80B, TLOADA/TCOMP pipelined, y3 stored as F32 DWORDS to d_out
// (full 64-B segments per lane-group — the R5 bf16 scalar stores were the
// 2.1x write-amplification regression). Fused bias + BN partials.
// ---------------------------------------------------------------------------
#define TTT    20
#define TCOLS  (TTT*V_)         // 500
#define SLABC  712              // 500 + 200 halo + 12 overrun pad
#define TTILES (T_/TTT)         // 15
#define NBLK   (N_*TTILES)      // 960

#define TLOADA(dst, kt_) { \
    _Pragma("unroll") \
    for (int mt = 0; mt < 4; ++mt) \
        dst[mt] = *(const bf16x8*)(Wtb + (size_t)(kt_)*4096 + (mt*16 + l15)*64 \
                                   + h*32 + lq*8); }

#define TCOMP(a_, kt_) { \
    _Pragma("unroll") \
    for (int nf = 0; nf < 8; ++nf) { \
        int col = colw + nf*16 + l15 + (kt_)*25; \
        bf16x8 b = *(const bf16x8*)((const char*)slab + col*80 + lq*16); \
        _Pragma("unroll") \
        for (int mt = 0; mt < 4; ++mt) \
            acc[mt][nf] = __builtin_amdgcn_mfma_f32_16x16x32_bf16( \
                a_[mt], b, acc[mt][nf], 0, 0, 0); } }

__global__ __launch_bounds__(256, 2) void tcn_kernel(
    const unsigned short* __restrict__ y2, const unsigned short* __restrict__ Wtb,
    const float* __restrict__ bt,
    float* __restrict__ y3f, float* __restrict__ psum, float* __restrict__ psq)
{
    __shared__ unsigned short slab[SLABC*40];   // 56,960 B
    __shared__ float s_sum[64], s_sq[64];

    const int tid = threadIdx.x;
    const int n  = blockIdx.x / TTILES;
    const int t0 = (blockIdx.x % TTILES) * TTT;
    const int lane = tid & 63, wave = tid >> 6;
    const int l15 = lane & 15, lq = lane >> 4;
    const int colw = wave * 128;

    if (tid < 64) { s_sum[tid] = 0.f; s_sq[tid] = 0.f; }

    const int lo = (t0 < PAD_) ? (PAD_ - t0)*V_ : 0;
    const int hi = (t0 + TTT + PAD_ > T_) ? (T_ + PAD_ - t0)*V_ : SLABC;
    const long gbase = ((long)n*T_*V_ + (long)(t0 - PAD_)*V_)*64;

    f32x4 acc[4][8] = {};

    #pragma unroll
    for (int h = 0; h < 2; ++h) {
        __syncthreads();
        for (int i = tid; i < SLABC*4; i += 256) {
            int col = i >> 2, ck = i & 3;
            float4 val = {0.f, 0.f, 0.f, 0.f};
            if (col >= lo && col < hi)
                val = *(const float4*)(y2 + gbase + (long)col*64 + h*32 + ck*8);
            *(float4*)((char*)slab + col*80 + ck*16) = val;
        }
        __syncthreads();
        bf16x8 aA[4], aB[4];
        TLOADA(aA, 0);
        #pragma unroll
        for (int kt = 0; kt < 9; ++kt) {
            if ((kt & 1) == 0) {
                if (kt < 8) TLOADA(aB, kt + 1);
                TCOMP(aA, kt);
            } else {
                if (kt < 8) TLOADA(aA, kt + 1);
                TCOMP(aB, kt);
            }
        }
    }

    // epilogue: bias + F32 DWORD stores + BN partials
    #pragma unroll
    for (int mt = 0; mt < 4; ++mt) {
        #pragma unroll
        for (int r = 0; r < 4; ++r) {
            const int o = mt*16 + lq*4 + r;
            const float bias = bt[o];
            float ls = 0.f, lsq = 0.f;
            #pragma unroll
            for (int nf = 0; nf < 8; ++nf) {
                int ocol = colw + nf*16 + l15;
                if (ocol < TCOLS) {
                    float val = acc[mt][nf][r] + bias;
                    y3f[(size_t)(n*C_ + o)*(T_*V_) + t0*V_ + ocol] = val;
                    ls += val; lsq += val*val;
                }
            }
            atomicAdd(&s_sum[o], ls);
            atomicAdd(&s_sq[o], lsq);
        }
    }
    __syncthreads();
    if (tid < 64) {
        psum[(size_t)tid*NBLK + blockIdx.x] = s_sum[tid];
        psq [(size_t)tid*NBLK + blockIdx.x] = s_sq [tid];
    }
}

// ---------------------------------------------------------------------------
// stats: reduce partials -> per-channel scale/shift
// ---------------------------------------------------------------------------
__global__ __launch_bounds__(256) void stats_kernel(
    const float* __restrict__ psum, const float* __restrict__ psq,
    const float* __restrict__ gamma, const float* __restrict__ beta,
    float* __restrict__ sb)
{
    const int o = blockIdx.x;
    const int tid = threadIdx.x;
    float s = 0.f, q = 0.f;
    for (int i = tid; i < NBLK; i += 256) {
        s += psum[(size_t)o*NBLK + i];
        q += psq [(size_t)o*NBLK + i];
    }
    __shared__ float rs[256], rq[256];
    rs[tid] = s; rq[tid] = q;
    __syncthreads();
    for (int off = 128; off > 0; off >>= 1) {
        if (tid < off) { rs[tid] += rs[tid + off]; rq[tid] += rq[tid + off]; }
        __syncthreads();
    }
    if (tid == 0) {
        const float cnt = (float)(N_ * T_ * V_);
        float mean = rs[0] / cnt;
        float var  = rq[0] / cnt - mean * mean;
        float rstd = rsqrtf(var + 1e-5f);
        float sc   = gamma[o] * rstd;
        sb[o]      = sc;
        sb[C_ + o] = beta[o] - mean * sc;
    }
}

// ---------------------------------------------------------------------------
// BN + residual + ReLU, in place on d_out (f32 y3), grid-stride
// ---------------------------------------------------------------------------
__global__ __launch_bounds__(256) void bn_res_relu_f32_kernel(
    const float* __restrict__ x, const float* __restrict__ sb,
    float* __restrict__ y)
{
    const size_t total4 = (size_t)N_ * C_ * T_ * V_ / 4;  // 7,680,000
    const size_t stride = (size_t)gridDim.x * 256;
    for (size_t i4 = (size_t)blockIdx.x * 256 + threadIdx.x; i4 < total4; i4 += stride) {
        const int c = (int)((i4 / (T_ * V_ / 4)) % C_);
        const float sc = sb[c], sh = sb[C_ + c];
        float4 yv = ((const float4*)y)[i4];
        float4 xv = ((const float4*)x)[i4];
        float4 o;
        o.x = fmaxf(yv.x * sc + sh + xv.x, 0.0f);
        o.y = fmaxf(yv.y * sc + sh + xv.y, 0.0f);
        o.z = fmaxf(yv.z * sc + sh + xv.z, 0.0f);
        o.w = fmaxf(yv.w * sc + sh + xv.w, 0.0f);
        ((float4*)y)[i4] = o;
    }
}

// ---------------------------------------------------------------------------
extern "C" void kernel_launch(void* const* d_in, const int* in_sizes, int n_in,
                              void* d_out, int out_size, void* d_ws, size_t ws_size,
                              hipStream_t stream)
{
    const float* x     = (const float*)d_in[0];
    const float* A     = (const float*)d_in[1];
    const float* wg    = (const float*)d_in[2];
    const float* bg    = (const float*)d_in[3];
    const float* wt    = (const float*)d_in[4];
    const float* bt    = (const float*)d_in[5];
    const float* gamma = (const float*)d_in[6];
    const float* beta  = (const float*)d_in[7];
    float* out = (float*)d_out;

    char* wsb = (char*)d_ws;
    const size_t Y2B = 61440000;                 // y2 bf16
    const size_t PSB = (size_t)C_ * NBLK * 4;    // 245,760 each

    unsigned short* y2     = (unsigned short*)wsb;
    float* psum            = (float*)(wsb + Y2B);
    float* psq             = (float*)(wsb + Y2B + PSB);
    float* sb              = (float*)(wsb + Y2B + 2*PSB);
    unsigned short* Wtb    = (unsigned short*)(wsb + Y2B + 2*PSB + 512);
    unsigned short* Wgbt   = (unsigned short*)(wsb + Y2B + 2*PSB + 512 + 73728);
    unsigned short* bias2b = (unsigned short*)(wsb + Y2B + 2*PSB + 512 + 73728 + 24576);
    unsigned short* Abt    = (unsigned short*)(wsb + Y2B + 2*PSB + 512 + 73728 + 24576 + 3200);

    prep_kernel<<<214, 256, 0, stream>>>(wt, wg, bg, A, Wtb, Wgbt, bias2b, Abt);
    gcn_kernel<<<NGBLK, 256, 0, stream>>>(x, Wgbt, Abt, bias2b, y2);
    tcn_kernel<<<NBLK, 256, 0, stream>>>(y2, Wtb, bt, out, psum, psq);
    stats_kernel<<<C_, 256, 0, stream>>>(psum, psq, gamma, beta, sb);
    bn_res_relu_f32_kernel<<<2048, 256, 0, stream>>>(x, sb, out);
}